// Round 3
// baseline (485.606 us; speedup 1.0000x reference)
//
#include <hip/hip_runtime.h>
#include <hip/hip_bf16.h>

typedef unsigned short u16;
typedef __attribute__((ext_vector_type(8))) short short8;     // 8 bf16 (4 VGPR) MFMA frag
typedef __attribute__((ext_vector_type(4))) float f32x4;      // MFMA accum
typedef __attribute__((ext_vector_type(8))) unsigned short ushort8v;
typedef __attribute__((ext_vector_type(4))) unsigned short ushort4v;

#define DEV static __device__ __forceinline__

DEV float bf2f(u16 u) { unsigned int v = ((unsigned int)u) << 16; float f; __builtin_memcpy(&f, &v, 4); return f; }
DEV u16 f2bf(float f) { unsigned int v; __builtin_memcpy(&v, &f, 4); v += 0x7FFFu + ((v >> 16) & 1u); return (u16)(v >> 16); }

#define MFMA(a, b, c) __builtin_amdgcn_mfma_f32_16x16x32_bf16((a), (b), (c), 0, 0, 0)

// async global->LDS, 16B per lane; LDS dest is wave-uniform base + lane*16 (linear!)
#define GLOAD_LDS(g, l) __builtin_amdgcn_global_load_lds( \
    (const __attribute__((address_space(1))) unsigned int*)(g), \
    (__attribute__((address_space(3))) unsigned int*)(l), 16, 0, 0)

// ---------------------------------------------------------------- cvt fp32->bf16 (W only)
__global__ __launch_bounds__(256) void cvt_bf16(const float* __restrict__ in,
                                                u16* __restrict__ out, int n4) {
  int i = blockIdx.x * 256 + threadIdx.x;
  if (i >= n4) return;
  float4 v = ((const float4*)in)[i];
  ushort4v o;
  o[0] = f2bf(v.x); o[1] = f2bf(v.y); o[2] = f2bf(v.z); o[3] = f2bf(v.w);
  ((ushort4v*)out)[i] = o;
}

// swizzled As address (row-stride 32 u16 = 64B, XOR bits 4-6 with row&7); 16B aligned
DEV u16* as_addr(u16* As, int row, int col) {
  int byte = (row * 64 + col * 2) ^ ((row & 7) << 4);
  return (u16*)((char*)As + byte);
}
DEV const u16* as_caddr(const u16* As, int row, int col) {
  int byte = (row * 64 + col * 2) ^ ((row & 7) << 4);
  return (const u16*)((const char*)As + byte);
}

// ---------------------------------------------------------------- QKV GEMM
// C[i,e] = sum_d X[i,d]*W[e,d]; i in 16384, e in 3072, K=1024. A: fp32 reg-staged+cvt;
// B: bf16 global_load_lds. Writes head-major bf16 Q/K/V.
__global__ __launch_bounds__(256, 2) void gemm_qkv(
    const float* __restrict__ X, const u16* __restrict__ W,
    u16* __restrict__ Qb, u16* __restrict__ Kb, u16* __restrict__ Vb)
{
  __shared__ u16 As[128 * 32];   // XOR-swizzled
  __shared__ u16 Bs[128 * 32];   // linear (global_load_lds dest)
  const int K = 1024;
  int t = threadIdx.x, lane = t & 63, wave = t >> 6;
  int bm = blockIdx.x, bn = blockIdx.y;

  // A staging: 128 rows x 32 k fp32; 2 threads/row, 16 fp32 each
  int arow = t >> 1, acseg = (t & 1) * 16;
  const float* gx = X + (size_t)(bm * 128 + arow) * K + acseg;
  // B staging: rows t>>2 (0..63) + 64, 8 u16 each, linear LDS
  int brow = t >> 2, bcol = (t & 3) * 8;
  const u16* gb0 = W + (size_t)(bn * 128 + brow) * K + bcol;
  const u16* gb1 = gb0 + (size_t)64 * K;
  u16* lb0 = Bs + wave * 512;
  u16* lb1 = Bs + 2048 + wave * 512;

  int wm = (wave & 1) * 64, wn = (wave >> 1) * 64;
  int fr = lane & 15, fk = (lane >> 4) * 8;

  f32x4 acc[4][4];
#pragma unroll
  for (int i = 0; i < 4; ++i)
#pragma unroll
    for (int j = 0; j < 4; ++j) acc[i][j] = (f32x4){0.f, 0.f, 0.f, 0.f};

  for (int k0 = 0; k0 < K; k0 += 32) {
    GLOAD_LDS(gb0, lb0); GLOAD_LDS(gb1, lb1);
    gb0 += 32; gb1 += 32;
    float4 f0 = *(const float4*)(gx + 0);
    float4 f1 = *(const float4*)(gx + 4);
    float4 f2 = *(const float4*)(gx + 8);
    float4 f3 = *(const float4*)(gx + 12);
    gx += 32;
    ushort8v a0, a1;
    a0[0] = f2bf(f0.x); a0[1] = f2bf(f0.y); a0[2] = f2bf(f0.z); a0[3] = f2bf(f0.w);
    a0[4] = f2bf(f1.x); a0[5] = f2bf(f1.y); a0[6] = f2bf(f1.z); a0[7] = f2bf(f1.w);
    a1[0] = f2bf(f2.x); a1[1] = f2bf(f2.y); a1[2] = f2bf(f2.z); a1[3] = f2bf(f2.w);
    a1[4] = f2bf(f3.x); a1[5] = f2bf(f3.y); a1[6] = f2bf(f3.z); a1[7] = f2bf(f3.w);
    *(ushort8v*)as_addr(As, arow, acseg)     = a0;
    *(ushort8v*)as_addr(As, arow, acseg + 8) = a1;
    __syncthreads();
    short8 af[4], bfv[4];
#pragma unroll
    for (int i = 0; i < 4; ++i) af[i] = *(const short8*)as_caddr(As, wm + i * 16 + fr, fk);
#pragma unroll
    for (int j = 0; j < 4; ++j) bfv[j] = *(const short8*)&Bs[(wn + j * 16 + fr) * 32 + fk];
#pragma unroll
    for (int i = 0; i < 4; ++i)
#pragma unroll
      for (int j = 0; j < 4; ++j) acc[i][j] = MFMA(af[i], bfv[j], acc[i][j]);
    __syncthreads();
  }

  int r4 = (lane >> 4) * 4, c0 = lane & 15;
#pragma unroll
  for (int j = 0; j < 4; ++j) {
    int gcol = bn * 128 + wn + j * 16 + c0;
    int s = gcol >> 10, rem = gcol & 1023;
    int h = rem >> 6, dh = rem & 63;
    u16* dst = (s == 0) ? Qb : ((s == 1) ? Kb : Vb);
#pragma unroll
    for (int i = 0; i < 4; ++i)
#pragma unroll
      for (int r = 0; r < 4; ++r) {
        int grow = bm * 128 + wm + i * 16 + r4 + r;
        int b = grow >> 12, n = grow & 4095;
        dst[((((size_t)(b * 16 + h) << 12) | n) << 6) | dh] = f2bf(acc[i][j][r]);
      }
  }
}

// ---------------------------------------------------------------- qa logits + softmax over M
// P1[b,h,n,m] = softmax_m( q[n,:]·(a[m,:]*SCALE) ); a staged from fp32. block=(nb:64 rows, h, b)
__global__ __launch_bounds__(256) void qa_softmax(
    const u16* __restrict__ Qb, const float* __restrict__ At, u16* __restrict__ P1)
{
  __shared__ u16 qs[64 * 72];
  __shared__ u16 as_[128 * 72];
  int t = threadIdx.x, lane = t & 63, wave = t >> 6;
  int nb = blockIdx.x, h = blockIdx.y, b = blockIdx.z;
  const u16* qbase = Qb + ((size_t)(b * 16 + h) * 4096 + nb * 64) * 64;
  const float* abase = At + (size_t)h * 8192;
  {
    int r = t >> 2, c = (t & 3) * 16;          // q: 64 rows, 16 u16 per thread
    *(ushort8v*)&qs[r * 72 + c]     = *(const ushort8v*)&qbase[(size_t)r * 64 + c];
    *(ushort8v*)&qs[r * 72 + c + 8] = *(const ushort8v*)&qbase[(size_t)r * 64 + c + 8];
    int ar = t >> 1, ac = (t & 1) * 32;        // a: 128 rows, 32 fp32 per thread
#pragma unroll
    for (int j = 0; j < 4; ++j) {
      float4 fa = *(const float4*)&abase[(size_t)ar * 64 + ac + j * 8];
      float4 fb = *(const float4*)&abase[(size_t)ar * 64 + ac + j * 8 + 4];
      ushort8v o;
      o[0] = f2bf(fa.x * 0.125f); o[1] = f2bf(fa.y * 0.125f);
      o[2] = f2bf(fa.z * 0.125f); o[3] = f2bf(fa.w * 0.125f);
      o[4] = f2bf(fb.x * 0.125f); o[5] = f2bf(fb.y * 0.125f);
      o[6] = f2bf(fb.z * 0.125f); o[7] = f2bf(fb.w * 0.125f);
      *(ushort8v*)&as_[ar * 72 + ac + j * 8] = o;
    }
  }
  __syncthreads();
  int fr = lane & 15, fk = (lane >> 4) * 8;
  f32x4 acc[8];
#pragma unroll
  for (int f = 0; f < 8; ++f) acc[f] = (f32x4){0.f, 0.f, 0.f, 0.f};
  short8 aq[2];
#pragma unroll
  for (int kk = 0; kk < 2; ++kk) aq[kk] = *(const short8*)&qs[(wave * 16 + fr) * 72 + kk * 32 + fk];
#pragma unroll
  for (int f = 0; f < 8; ++f) {
#pragma unroll
    for (int kk = 0; kk < 2; ++kk) {
      short8 bv = *(const short8*)&as_[(f * 16 + fr) * 72 + kk * 32 + fk];
      acc[f] = MFMA(aq[kk], bv, acc[f]);
    }
  }
#pragma unroll
  for (int r = 0; r < 4; ++r) {
    float mx = acc[0][r];
#pragma unroll
    for (int f = 1; f < 8; ++f) mx = fmaxf(mx, acc[f][r]);
#pragma unroll
    for (int d = 1; d < 16; d <<= 1) mx = fmaxf(mx, __shfl_xor(mx, d));
    float s = 0.f;
#pragma unroll
    for (int f = 0; f < 8; ++f) { float e = __expf(acc[f][r] - mx); acc[f][r] = e; s += e; }
#pragma unroll
    for (int d = 1; d < 16; d <<= 1) s += __shfl_xor(s, d);
    float inv = 1.f / s;
#pragma unroll
    for (int f = 0; f < 8; ++f) acc[f][r] *= inv;
  }
  size_t pbase = ((size_t)(b * 16 + h) * 4096 + nb * 64 + wave * 16) * 128;
#pragma unroll
  for (int f = 0; f < 8; ++f)
#pragma unroll
    for (int r = 0; r < 4; ++r)
      P1[pbase + (size_t)((lane >> 4) * 4 + r) * 128 + f * 16 + (lane & 15)] = f2bf(acc[f][r]);
}

// ---------------------------------------------------------------- ak logits
// L2[b,h,m,n] = (a[m,:]*SCALE)·k[n,:]; block=(nb:128 cols, h, b)
__global__ __launch_bounds__(256) void ak_logits(
    const u16* __restrict__ Kb, const float* __restrict__ At, u16* __restrict__ L2)
{
  __shared__ u16 ks[128 * 72];
  __shared__ u16 as_[128 * 72];
  int t = threadIdx.x, lane = t & 63, wave = t >> 6;
  int nb = blockIdx.x, h = blockIdx.y, b = blockIdx.z;
  const u16* kbase = Kb + ((size_t)(b * 16 + h) * 4096 + nb * 128) * 64;
  const float* abase = At + (size_t)h * 8192;
  {
    int r = t >> 1, c = (t & 1) * 32;          // k: 128 rows, 32 u16 per thread
#pragma unroll
    for (int j = 0; j < 4; ++j)
      *(ushort8v*)&ks[r * 72 + c + j * 8] = *(const ushort8v*)&kbase[(size_t)r * 64 + c + j * 8];
#pragma unroll
    for (int j = 0; j < 4; ++j) {
      float4 fa = *(const float4*)&abase[(size_t)r * 64 + c + j * 8];
      float4 fb = *(const float4*)&abase[(size_t)r * 64 + c + j * 8 + 4];
      ushort8v o;
      o[0] = f2bf(fa.x * 0.125f); o[1] = f2bf(fa.y * 0.125f);
      o[2] = f2bf(fa.z * 0.125f); o[3] = f2bf(fa.w * 0.125f);
      o[4] = f2bf(fb.x * 0.125f); o[5] = f2bf(fb.y * 0.125f);
      o[6] = f2bf(fb.z * 0.125f); o[7] = f2bf(fb.w * 0.125f);
      *(ushort8v*)&as_[r * 72 + c + j * 8] = o;
    }
  }
  __syncthreads();
  int fr = lane & 15, fk = (lane >> 4) * 8;
  int wm = (wave & 1) * 64, wn = (wave >> 1) * 64;
  short8 am[4][2];
#pragma unroll
  for (int mi = 0; mi < 4; ++mi)
#pragma unroll
    for (int kk = 0; kk < 2; ++kk)
      am[mi][kk] = *(const short8*)&as_[(wm + mi * 16 + fr) * 72 + kk * 32 + fk];
  f32x4 acc[4][4];
#pragma unroll
  for (int i = 0; i < 4; ++i)
#pragma unroll
    for (int j = 0; j < 4; ++j) acc[i][j] = (f32x4){0.f, 0.f, 0.f, 0.f};
#pragma unroll
  for (int nj = 0; nj < 4; ++nj) {
    short8 bk0 = *(const short8*)&ks[(wn + nj * 16 + fr) * 72 + 0 + fk];
    short8 bk1 = *(const short8*)&ks[(wn + nj * 16 + fr) * 72 + 32 + fk];
#pragma unroll
    for (int mi = 0; mi < 4; ++mi) acc[mi][nj] = MFMA(am[mi][0], bk0, acc[mi][nj]);
#pragma unroll
    for (int mi = 0; mi < 4; ++mi) acc[mi][nj] = MFMA(am[mi][1], bk1, acc[mi][nj]);
  }
  size_t rowbase = (size_t)(b * 16 + h) * 128;
#pragma unroll
  for (int mi = 0; mi < 4; ++mi)
#pragma unroll
    for (int nj = 0; nj < 4; ++nj)
#pragma unroll
      for (int r = 0; r < 4; ++r) {
        int m = wm + mi * 16 + (lane >> 4) * 4 + r;
        int n = nb * 128 + wn + nj * 16 + (lane & 15);
        L2[(rowbase + m) * 4096 + n] = f2bf(acc[mi][nj][r]);
      }
}

// ---------------------------------------------------------------- softmax over N (rows of 4096), in place
__global__ __launch_bounds__(256) void softmax_rows(u16* __restrict__ L)
{
  __shared__ float red[8];
  int t = threadIdx.x, lane = t & 63, wave = t >> 6;
  size_t base = (size_t)blockIdx.x * 4096;
  float v[16];
  ushort8v u0 = *(const ushort8v*)&L[base + t * 8];
  ushort8v u1 = *(const ushort8v*)&L[base + 2048 + t * 8];
#pragma unroll
  for (int j = 0; j < 8; ++j) { v[j] = bf2f(u0[j]); v[8 + j] = bf2f(u1[j]); }
  float mx = v[0];
#pragma unroll
  for (int j = 1; j < 16; ++j) mx = fmaxf(mx, v[j]);
#pragma unroll
  for (int d = 1; d < 64; d <<= 1) mx = fmaxf(mx, __shfl_xor(mx, d));
  if (lane == 0) red[wave] = mx;
  __syncthreads();
  mx = fmaxf(fmaxf(red[0], red[1]), fmaxf(red[2], red[3]));
  float s = 0.f;
#pragma unroll
  for (int j = 0; j < 16; ++j) { v[j] = __expf(v[j] - mx); s += v[j]; }
#pragma unroll
  for (int d = 1; d < 64; d <<= 1) s += __shfl_xor(s, d);
  if (lane == 0) red[4 + wave] = s;
  __syncthreads();
  float inv = 1.f / (red[4] + red[5] + red[6] + red[7]);
  ushort8v o0, o1;
#pragma unroll
  for (int j = 0; j < 8; ++j) { o0[j] = f2bf(v[j] * inv); o1[j] = f2bf(v[8 + j] * inv); }
  *(ushort8v*)&L[base + t * 8] = o0;
  *(ushort8v*)&L[base + 2048 + t * 8] = o1;
}

// ---------------------------------------------------------------- talking-heads mix, in place
// out[b,g,e] = sum_h W[g,h]*in[b,h,e]; block owns (b, 1024-elem chunk) for ALL h,g; thread owns 4 cols
__global__ __launch_bounds__(256) void mix_heads(u16* __restrict__ P, const float* __restrict__ Wm)
{
  __shared__ float w[256];
  int t = threadIdx.x;
  w[t] = Wm[t];
  __syncthreads();
  int b = blockIdx.y;
  size_t pb = (size_t)b * 16 * 524288 + (size_t)blockIdx.x * 1024 + t * 4;
  float acc[16][4];
#pragma unroll
  for (int g = 0; g < 16; ++g)
#pragma unroll
    for (int j = 0; j < 4; ++j) acc[g][j] = 0.f;
  for (int hh = 0; hh < 16; ++hh) {
    ushort4v u = *(const ushort4v*)&P[pb + (size_t)hh * 524288];
    float v0 = bf2f(u[0]), v1 = bf2f(u[1]), v2 = bf2f(u[2]), v3 = bf2f(u[3]);
#pragma unroll
    for (int g = 0; g < 16; ++g) {
      float wg = w[g * 16 + hh];
      acc[g][0] += wg * v0; acc[g][1] += wg * v1;
      acc[g][2] += wg * v2; acc[g][3] += wg * v3;
    }
  }
#pragma unroll
  for (int g = 0; g < 16; ++g) {
    ushort4v o;
    o[0] = f2bf(acc[g][0]); o[1] = f2bf(acc[g][1]);
    o[2] = f2bf(acc[g][2]); o[3] = f2bf(acc[g][3]);
    *(ushort4v*)&P[pb + (size_t)g * 524288] = o;
  }
}

// ---------------------------------------------------------------- V transpose: VT[bh,d,n] = V[bh,n,d]
__global__ __launch_bounds__(256) void transpose_v(const u16* __restrict__ V, u16* __restrict__ VT)
{
  __shared__ u16 tile[64 * 72];
  int t = threadIdx.x;
  int nb = blockIdx.x, h = blockIdx.y, b = blockIdx.z;
  size_t vbase = ((size_t)(b * 16 + h) * 4096 + nb * 64) * 64;
  int r = t >> 3, c = (t & 7) * 8;
#pragma unroll
  for (int it = 0; it < 2; ++it)
    *(ushort8v*)&tile[(it * 32 + r) * 72 + c] = *(const ushort8v*)&V[vbase + (size_t)(it * 32 + r) * 64 + c];
  __syncthreads();
  size_t tbase = ((size_t)(b * 16 + h) * 64) * 4096 + nb * 64;
#pragma unroll
  for (int it = 0; it < 2; ++it) {
    int d = it * 32 + (t >> 3);
    int n8 = (t & 7) * 8;
    ushort8v o;
#pragma unroll
    for (int j = 0; j < 8; ++j) o[j] = tile[(n8 + j) * 72 + d];
    *(ushort8v*)&VT[tbase + (size_t)d * 4096 + n8] = o;
  }
}

// ---------------------------------------------------------------- ag partial: C[m,d] = sum_{n in ks} P2m[m,n]*VT[d,n]
__global__ __launch_bounds__(256) void ag_partial(
    const u16* __restrict__ P2, const u16* __restrict__ VT, float* __restrict__ agp)
{
  __shared__ u16 ps[128 * 40];
  __shared__ u16 vs[64 * 40];
  int t = threadIdx.x, lane = t & 63, wave = t >> 6;
  int ks = blockIdx.x, g = blockIdx.y, b = blockIdx.z;
  size_t pbase = (size_t)(b * 16 + g) * 128 * 4096;
  size_t vbase = (size_t)(b * 16 + g) * 64 * 4096;
  int fr = lane & 15, fk = (lane >> 4) * 8;
  int wm = (wave & 1) * 64, wd = (wave >> 1) * 32;
  int pr = t >> 1, pc = (t & 1) * 16;
  int vr = t >> 2, vc = (t & 3) * 8;
  f32x4 acc[4][2];
#pragma unroll
  for (int i = 0; i < 4; ++i)
#pragma unroll
    for (int j = 0; j < 2; ++j) acc[i][j] = (f32x4){0.f, 0.f, 0.f, 0.f};
  for (int k0 = 0; k0 < 1024; k0 += 32) {
    size_t ncol = (size_t)ks * 1024 + k0;
    *(ushort8v*)&ps[pr * 40 + pc]     = *(const ushort8v*)&P2[pbase + (size_t)pr * 4096 + ncol + pc];
    *(ushort8v*)&ps[pr * 40 + pc + 8] = *(const ushort8v*)&P2[pbase + (size_t)pr * 4096 + ncol + pc + 8];
    *(ushort8v*)&vs[vr * 40 + vc]     = *(const ushort8v*)&VT[vbase + (size_t)vr * 4096 + ncol + vc];
    __syncthreads();
    short8 am[4], bv[2];
#pragma unroll
    for (int mi = 0; mi < 4; ++mi) am[mi] = *(const short8*)&ps[(wm + mi * 16 + fr) * 40 + fk];
#pragma unroll
    for (int dj = 0; dj < 2; ++dj) bv[dj] = *(const short8*)&vs[(wd + dj * 16 + fr) * 40 + fk];
#pragma unroll
    for (int mi = 0; mi < 4; ++mi)
#pragma unroll
      for (int dj = 0; dj < 2; ++dj) acc[mi][dj] = MFMA(am[mi], bv[dj], acc[mi][dj]);
    __syncthreads();
  }
  size_t obase = ((size_t)ks * 64 + b * 16 + g) * 8192;
#pragma unroll
  for (int mi = 0; mi < 4; ++mi)
#pragma unroll
    for (int dj = 0; dj < 2; ++dj)
#pragma unroll
      for (int r = 0; r < 4; ++r) {
        int m = wm + mi * 16 + (lane >> 4) * 4 + r;
        int d = wd + dj * 16 + (lane & 15);
        agp[obase + (size_t)m * 64 + d] = acc[mi][dj][r];
      }
}

// ---------------------------------------------------------------- reduce 4 partials -> agT[bg,d,m] bf16
__global__ __launch_bounds__(256) void ag_reduce(const float* __restrict__ agp, u16* __restrict__ agT)
{
  size_t i = (size_t)blockIdx.x * 256 + threadIdx.x;  // 0..524287
  float s = agp[i] + agp[i + 524288] + agp[i + 1048576] + agp[i + 1572864];
  int d = (int)(i & 63);
  int m = (int)((i >> 6) & 127);
  size_t bg = i >> 13;
  agT[(bg * 64 + d) * 128 + m] = f2bf(s);
}

// ---------------------------------------------------------------- out: C[n,d] = sum_m P1m[n,m]*agT[d,m], fp32 out
__global__ __launch_bounds__(256) void out_gemm(
    const u16* __restrict__ P1, const u16* __restrict__ agT, float* __restrict__ Out)
{
  __shared__ u16 ps[128 * 136];
  __shared__ u16 gs[64 * 136];
  int t = threadIdx.x, lane = t & 63, wave = t >> 6;
  int nb = blockIdx.x, g = blockIdx.y, b = blockIdx.z;
  size_t p1base = ((size_t)(b * 16 + g) * 4096 + nb * 128) * 128;
  size_t gbase = (size_t)(b * 16 + g) * 8192;
  int r = t >> 4, c = (t & 15) * 8;
#pragma unroll
  for (int it = 0; it < 8; ++it)
    *(ushort8v*)&ps[(it * 16 + r) * 136 + c] = *(const ushort8v*)&P1[p1base + (size_t)(it * 16 + r) * 128 + c];
#pragma unroll
  for (int it = 0; it < 4; ++it)
    *(ushort8v*)&gs[(it * 16 + r) * 136 + c] = *(const ushort8v*)&agT[gbase + (size_t)(it * 16 + r) * 128 + c];
  __syncthreads();
  int fr = lane & 15, fk = (lane >> 4) * 8;
  int wm = (wave & 1) * 64, wd = (wave >> 1) * 32;
  f32x4 acc[4][2];
#pragma unroll
  for (int i = 0; i < 4; ++i)
#pragma unroll
    for (int j = 0; j < 2; ++j) acc[i][j] = (f32x4){0.f, 0.f, 0.f, 0.f};
#pragma unroll
  for (int kk = 0; kk < 4; ++kk) {
    short8 am[4], bv[2];
#pragma unroll
    for (int mi = 0; mi < 4; ++mi) am[mi] = *(const short8*)&ps[(wm + mi * 16 + fr) * 136 + kk * 32 + fk];
#pragma unroll
    for (int dj = 0; dj < 2; ++dj) bv[dj] = *(const short8*)&gs[(wd + dj * 16 + fr) * 136 + kk * 32 + fk];
#pragma unroll
    for (int mi = 0; mi < 4; ++mi)
#pragma unroll
      for (int dj = 0; dj < 2; ++dj) acc[mi][dj] = MFMA(am[mi], bv[dj], acc[mi][dj]);
  }
  size_t ob = ((size_t)(b * 16 + g) * 4096 + nb * 128) * 64;
#pragma unroll
  for (int mi = 0; mi < 4; ++mi)
#pragma unroll
    for (int dj = 0; dj < 2; ++dj)
#pragma unroll
      for (int r2 = 0; r2 < 4; ++r2) {
        int row = wm + mi * 16 + (lane >> 4) * 4 + r2;
        int col = wd + dj * 16 + (lane & 15);
        Out[ob + (size_t)row * 64 + col] = acc[mi][dj][r2];
      }
}

// ---------------------------------------------------------------- launcher
// Workspace plan (192 MB total, liveness-overlapped; stream order serializes):
//   [0,64)    P1 [B,H,N,M] bf16 — head 6MB doubles as wb (dead before qa_softmax)
//   [64,128)  L2 [B,H,M,N] bf16 — upper half [96,128) doubles as Vb (dead before ak_logits)
//   [128,160) Qb [B,H,N,DH] bf16 — reused as VT [B,H,DH,N] after qa_softmax
//   [160,192) Kb [B,H,N,DH] bf16 — reused as agp(8MB)+agT(1MB) after ak_logits
extern "C" void kernel_launch(void* const* d_in, const int* in_sizes, int n_in,
                              void* d_out, int out_size, void* d_ws, size_t ws_size,
                              hipStream_t stream)
{
  const float* x   = (const float*)d_in[0];
  const float* at  = (const float*)d_in[1];
  const float* wf  = (const float*)d_in[2];
  const float* wqa = (const float*)d_in[3];
  const float* wak = (const float*)d_in[4];
  float* Out = (float*)d_out;
  char* ws = (char*)d_ws;
  const size_t MB = 1ull << 20;
  u16* P1  = (u16*)(ws + 0);
  u16* wb  = (u16*)(ws + 0);
  u16* L2  = (u16*)(ws + 64 * MB);
  u16* Vb  = (u16*)(ws + 96 * MB);
  u16* Qb  = (u16*)(ws + 128 * MB);
  u16* VT  = (u16*)(ws + 128 * MB);
  u16* Kb  = (u16*)(ws + 160 * MB);
  float* agp = (float*)(ws + 160 * MB);
  u16* agT = (u16*)(ws + 168 * MB);

  cvt_bf16<<<dim3(3072), dim3(256), 0, stream>>>(wf, wb, 786432);
  gemm_qkv<<<dim3(128, 24), dim3(256), 0, stream>>>(x, wb, Qb, Kb, Vb);
  qa_softmax<<<dim3(64, 16, 4), dim3(256), 0, stream>>>(Qb, at, P1);   // wb dead, P1 live
  transpose_v<<<dim3(64, 16, 4), dim3(256), 0, stream>>>(Vb, VT);      // Qb dead -> VT
  ak_logits<<<dim3(32, 16, 4), dim3(256), 0, stream>>>(Kb, at, L2);    // Vb dead, L2 live
  softmax_rows<<<dim3(8192), dim3(256), 0, stream>>>(L2);
  mix_heads<<<dim3(512, 4), dim3(256), 0, stream>>>(P1, wqa);
  mix_heads<<<dim3(512, 4), dim3(256), 0, stream>>>(L2, wak);
  ag_partial<<<dim3(4, 16, 4), dim3(256), 0, stream>>>(L2, VT, agp);   // Kb dead -> agp
  ag_reduce<<<dim3(2048), dim3(256), 0, stream>>>(agp, agT);
  out_gemm<<<dim3(32, 16, 4), dim3(256), 0, stream>>>(P1, agT, Out);
}